// Round 1
// baseline (570.654 us; speedup 1.0000x reference)
//
#include <hip/hip_runtime.h>
#include <stdint.h>

typedef __attribute__((ext_vector_type(8))) short short8;
typedef __attribute__((ext_vector_type(4))) float floatx4;

#define LDQ 136   // 128 + 8 bf16 pad -> 272B rows, 16B aligned, 2-way banks (free)

__device__ __forceinline__ uint16_t f32_to_bf16(float f) {
    uint32_t u = __builtin_bit_cast(uint32_t, f);
    u += 0x7FFFu + ((u >> 16) & 1u);   // RTNE
    return (uint16_t)(u >> 16);
}

// ---------------- Kernel 1: Householder Q, one wave per column ----------------
// Q = (I - b64 v64 v64^T) ... (I - b1 v1 v1^T) applied to I; columns independent:
// col c = sequence of reflections applied to e_c. Exact same fp32 op sequence
// per column as the reference scan.
__global__ __launch_bounds__(256) void hh_q_kernel(const float* __restrict__ vs,
                                                   uint16_t* __restrict__ Qrm,
                                                   uint16_t* __restrict__ Qt) {
    __shared__ float vsl[64 * 128];   // 32 KB
    int tid = threadIdx.x;
    const float4* vsv = (const float4*)vs;
    float4* vslv = (float4*)vsl;
#pragma unroll
    for (int i = 0; i < 8; ++i) vslv[tid + 256 * i] = vsv[tid + 256 * i];
    __syncthreads();

    int wave = tid >> 6, lane = tid & 63;
    int col = blockIdx.x * 4 + wave;          // 32 blocks * 4 waves = 128 cols
    float x0 = (lane == col) ? 1.f : 0.f;     // x[lane]
    float x1 = (lane + 64 == col) ? 1.f : 0.f;// x[lane+64]
    for (int k = 0; k < 64; ++k) {
        float v0 = vsl[k * 128 + lane];
        float v1 = vsl[k * 128 + 64 + lane];
        float d  = v0 * x0 + v1 * x1;   // partial v.x
        float vn = v0 * v0 + v1 * v1;   // partial v.v
#pragma unroll
        for (int m = 1; m < 64; m <<= 1) {
            d  += __shfl_xor(d, m, 64);
            vn += __shfl_xor(vn, m, 64);
        }
        float sfac = 2.f / (vn + 1e-8f) * d;
        x0 -= sfac * v0;
        x1 -= sfac * v1;
    }
    // Q[i][col] = x[i]
    Qrm[lane * 128 + col]        = f32_to_bf16(x0);
    Qrm[(lane + 64) * 128 + col] = f32_to_bf16(x1);
    Qt[col * 128 + lane]         = f32_to_bf16(x0);   // Qt[a][b] = Q[b][a]
    Qt[col * 128 + lane + 64]    = f32_to_bf16(x1);
}

// ---------------- Kernel 2: fused (x @ Q^T) -> RoPE -> (@ Q) ----------------
// One wave = one 16-row group (16 consecutive s for one (b,h,tensor)).
// GEMM1: A = rows of q/k from global (fp32->bf16), B[k][n]=Q[n][k] = LDS Qrm rows.
// RoPE in C-layout regs (d and d+64 live in acc[nt] / acc[nt+4], same lane/reg).
// C->A layout fix via per-wave LDS scratch. GEMM2: B[k][n]=Q[k][n]=Qt rows (global, L1-hot).
__global__ __launch_bounds__(256) void rope_rot_kernel(
    const float* __restrict__ qin, const float* __restrict__ kin,
    const float* __restrict__ cosp, const float* __restrict__ sinp,
    const uint16_t* __restrict__ Qrm, const uint16_t* __restrict__ Qt,
    float* __restrict__ outp) {

    __shared__ uint16_t Qlds[128 * LDQ];        // 34816 B
    __shared__ uint16_t scratch[4 * 16 * LDQ];  // 17408 B  (per-wave 16x136)

    int tid = threadIdx.x;
    // stage Q (bf16) into padded LDS rows, 16B chunks
    {
        const short8* qg = (const short8*)Qrm;
#pragma unroll
        for (int i = 0; i < 8; ++i) {
            int e8 = tid + i * 256;          // 2048 chunks of 8 elems
            int e = e8 * 8;
            int row = e >> 7, colq = e & 127;
            *(short8*)&Qlds[row * LDQ + colq] = qg[e8];
        }
    }
    __syncthreads();

    int bidx = blockIdx.x;
    int t   = bidx & 1;
    int h4  = (bidx >> 1) & 3;
    int s16 = (bidx >> 3) & 255;
    int b   = bidx >> 11;
    int wave = tid >> 6, lane = tid & 63;
    int h = h4 * 4 + wave;
    int x = lane & 15, g = lane >> 4;

    long rowbase = ((long)(b * 16 + h) * 4096 + s16 * 16);
    const float* src  = t ? kin : qin;
    const float* srow = src + rowbase * 128;
    float* drow = outp + (long)t * 33554432L + rowbase * 128;
    const float* crow = cosp + ((long)b * 4096 + (long)s16 * 16) * 128;
    const float* srw  = sinp + ((long)b * 4096 + (long)s16 * 16) * 128;

    floatx4 zero4 = {0.f, 0.f, 0.f, 0.f};
    floatx4 acc[8];
#pragma unroll
    for (int nt = 0; nt < 8; ++nt) acc[nt] = zero4;

    // ---- GEMM1: C1[m][d] = sum_k q[m][k] * Q[d][k] ----
#pragma unroll
    for (int kt = 0; kt < 4; ++kt) {
        const float* ap = srow + x * 128 + kt * 32 + g * 8;  // A[m=x][k..k+7]
        float4 a0 = *(const float4*)ap;
        float4 a1 = *(const float4*)(ap + 4);
        short8 af;
        af[0] = (short)f32_to_bf16(a0.x); af[1] = (short)f32_to_bf16(a0.y);
        af[2] = (short)f32_to_bf16(a0.z); af[3] = (short)f32_to_bf16(a0.w);
        af[4] = (short)f32_to_bf16(a1.x); af[5] = (short)f32_to_bf16(a1.y);
        af[6] = (short)f32_to_bf16(a1.z); af[7] = (short)f32_to_bf16(a1.w);
#pragma unroll
        for (int nt = 0; nt < 8; ++nt) {
            short8 bf = *(const short8*)&Qlds[(nt * 16 + x) * LDQ + kt * 32 + g * 8];
            acc[nt] = __builtin_amdgcn_mfma_f32_16x16x32_bf16(af, bf, acc[nt], 0, 0, 0);
        }
    }

    // ---- RoPE in C-layout regs; write bf16 to per-wave scratch in [m][d] ----
    uint16_t* sc = scratch + wave * 16 * LDQ;
#pragma unroll
    for (int nt = 0; nt < 8; ++nt) {
#pragma unroll
        for (int r = 0; r < 4; ++r) {
            int m = 4 * g + r;             // C-layout row
            int d = nt * 16 + x;           // C-layout col
            float c = crow[m * 128 + d];
            float s = srw[m * 128 + d];
            float v = (nt < 4) ? (acc[nt][r] * c - acc[nt + 4][r] * s)
                               : (acc[nt][r] * c + acc[nt - 4][r] * s);
            sc[m * LDQ + d] = f32_to_bf16(v);
        }
    }
    __syncthreads();

    // ---- GEMM2: out[m][e] = sum_k qrot[m][k] * Q[k][e] ----
#pragma unroll
    for (int nt = 0; nt < 8; ++nt) acc[nt] = zero4;
#pragma unroll
    for (int kt = 0; kt < 4; ++kt) {
        short8 af = *(const short8*)&sc[x * LDQ + kt * 32 + g * 8];   // A[m=x][k..]
#pragma unroll
        for (int nt = 0; nt < 8; ++nt) {
            // B[k][n] = Q[k][nt*16+x] = Qt[nt*16+x][k]  (global, 32KB, L1-resident)
            short8 bf = *(const short8*)&Qt[(nt * 16 + x) * 128 + kt * 32 + g * 8];
            acc[nt] = __builtin_amdgcn_mfma_f32_16x16x32_bf16(af, bf, acc[nt], 0, 0, 0);
        }
    }

    // ---- store fp32 ----
#pragma unroll
    for (int nt = 0; nt < 8; ++nt) {
#pragma unroll
        for (int r = 0; r < 4; ++r) {
            drow[(4 * g + r) * 128 + nt * 16 + x] = acc[nt][r];
        }
    }
}

extern "C" void kernel_launch(void* const* d_in, const int* in_sizes, int n_in,
                              void* d_out, int out_size, void* d_ws, size_t ws_size,
                              hipStream_t stream) {
    const float* q   = (const float*)d_in[0];
    const float* k   = (const float*)d_in[1];
    const float* cs  = (const float*)d_in[2];
    const float* sn  = (const float*)d_in[3];
    const float* vs  = (const float*)d_in[4];
    uint16_t* Qrm = (uint16_t*)d_ws;           // 128*128 bf16
    uint16_t* Qt  = Qrm + 128 * 128;           // transposed copy

    hh_q_kernel<<<32, 256, 0, stream>>>(vs, Qrm, Qt);
    // grid: (b, s16) outer, (h4, tensor) inner -> 8 adjacent blocks share a cos/sin tile
    rope_rot_kernel<<<8192, 256, 0, stream>>>(q, k, cs, sn, Qrm, Qt, (float*)d_out);
}